// Round 20
// baseline (117.700 us; speedup 1.0000x reference)
//
#include <hip/hip_runtime.h>
#include <hip/hip_bf16.h>

typedef float f32x4 __attribute__((ext_vector_type(4)));
typedef float f32x16 __attribute__((ext_vector_type(16)));
typedef long l64x2 __attribute__((ext_vector_type(2)));
typedef int i32x8 __attribute__((ext_vector_type(8)));
typedef unsigned short u16;
typedef unsigned char u8;

#define NB2 (-0.35f * 1.44269504088896340736f)
#define P2C (0.70f * 1.44269504088896340736f)
// MX-scaled fp8 e4m3 (cbsz=0, blgp=0), scales 1.0
#define MFS(a,b,c) __builtin_amdgcn_mfma_scale_f32_32x32x64_f8f6f4( \
    a, b, c, 0, 0, 0, 0x7F7F7F7F, 0, 0x7F7F7F7F)
// GEMM2: A=P (scale 1.0), B=W stored x64 (scale 2^-6 = E8M0 121 = 0x79)
#define MFS2(a,b,c) __builtin_amdgcn_mfma_scale_f32_32x32x64_f8f6f4( \
    a, b, c, 0, 0, 0, 0x7F7F7F7F, 0, 0x79797979)

__device__ __forceinline__ void pswap(unsigned &a, unsigned &b) {
  asm volatile("v_permlane32_swap_b32 %0, %1" : "+v"(a), "+v"(b));
}

__device__ __forceinline__ u8 f2e4m3(float f) {
  unsigned int u = __float_as_uint(f);
  u8 s = (u8)((u >> 24) & 0x80u);
  float a = fabsf(f);
  if (a >= 448.f) return s | 0x7E;
  if (a < 0.015625f) return s | (u8)(int)rintf(a * 512.f);
  unsigned int m = u & 0x7fffffffu;
  unsigned int r = m + 0x7FFFFu + ((m >> 20) & 1u);
  return s | (u8)((((r >> 23) - 120u) << 3) | ((r >> 20) & 7u));
}

__device__ __forceinline__ unsigned int pk4(float a, float b, float c, float d) {
#if __has_builtin(__builtin_amdgcn_cvt_pk_fp8_f32)
  int v = __builtin_amdgcn_cvt_pk_fp8_f32(a, b, 0, false);
  v = __builtin_amdgcn_cvt_pk_fp8_f32(c, d, v, true);
  return (unsigned int)v;
#else
  return (unsigned int)f2e4m3(a) | ((unsigned int)f2e4m3(b) << 8)
       | ((unsigned int)f2e4m3(c) << 16) | ((unsigned int)f2e4m3(d) << 24);
#endif
}

#define GLOAD_LDS(g, l) __builtin_amdgcn_global_load_lds( \
    (const __attribute__((address_space(1))) unsigned int*)(g), \
    (__attribute__((address_space(3))) unsigned int*)(l), 16, 0, 0)

// ---------- prep: x -> fp8 K=64 frag-stream [tile32][P(8)][lane(64)][32B] + xsq ----------
__global__ __launch_bounds__(512)
void prep_x8(const float* __restrict__ src, u8* __restrict__ dst,
             float* __restrict__ sq) {
  const int row = blockIdx.x * 8 + (threadIdx.x >> 6);
  const int i6 = threadIdx.x & 63;
  const float4* p = (const float4*)(src + (size_t)row * 512) + i6 * 2;
  float4 a = p[0], b = p[1];
  float ss = a.x*a.x + a.y*a.y + a.z*a.z + a.w*a.w
           + b.x*b.x + b.y*b.y + b.z*b.z + b.w*b.w;
  uint2 o;
  o.x = pk4(a.x, a.y, a.z, a.w);
  o.y = pk4(b.x, b.y, b.z, b.w);
  const int P = i6 >> 3, rem = i6 & 7;
  const int kh = rem >> 2;
  const int l = (kh << 5) | (row & 31);
  *(uint2*)(dst + (size_t)(row >> 5) * 16384 + P * 2048 + l * 32 + (rem & 3) * 8) = o;
  ss += __shfl_xor(ss, 1);  ss += __shfl_xor(ss, 2);
  ss += __shfl_xor(ss, 4);  ss += __shfl_xor(ss, 8);
  ss += __shfl_xor(ss, 16); ss += __shfl_xor(ss, 32);
  if (i6 == 0) sq[row] = ss;
}

// ---------- prep: centers -> fp8 K=64 frag-stream with 16B-unit XOR swizzle + csq ----------
__global__ __launch_bounds__(256)
void prep_cen(const float* __restrict__ cen, u8* __restrict__ cfr,
              float* __restrict__ csq) {
  const int t = threadIdx.x;
  const int c = blockIdx.x * 4 + (t >> 6);
  const int i6 = t & 63;
  const float* p = cen + (size_t)c * 512 + i6 * 8;
  float4 a = *(const float4*)p, b = *(const float4*)(p + 4);
  float ss = a.x*a.x + a.y*a.y + a.z*a.z + a.w*a.w
           + b.x*b.x + b.y*b.y + b.z*b.z + b.w*b.w;
  uint2 o;
  o.x = pk4(a.x, a.y, a.z, a.w);
  o.y = pk4(b.x, b.y, b.z, b.w);
  const int P = i6 >> 3, rem = i6 & 7;
  const int kh = rem >> 2;
  const int lc = c & 31;
  const int l = (kh << 5) | lc;
  const int u = (rem >> 1) & 1;
  const int sub = rem & 1;
  const int us = u ^ ((lc >> 2) & 1);
  *(uint2*)(cfr + (size_t)(c >> 5) * 16384 + P * 2048 + l * 32 + us * 16 + sub * 8) = o;
  ss += __shfl_xor(ss, 1);  ss += __shfl_xor(ss, 2);
  ss += __shfl_xor(ss, 4);  ss += __shfl_xor(ss, 8);
  ss += __shfl_xor(ss, 16); ss += __shfl_xor(ss, 32);
  if (i6 == 0) csq[c] = ss;
}

// ---------- prep: W [4096][128] f32 -> fp8(x64) MX B-operand pair-stream ----------
__global__ __launch_bounds__(256)
void prep_w(const float* __restrict__ W, u8* __restrict__ wfr) {
  __shared__ float t_[64 * 128];   // 32 KB
  const int pr = blockIdx.x;       // pair 0..63
  const int t = threadIdx.x;
#pragma unroll
  for (int it = 0; it < 32; ++it) {
    int idx = it * 256 + t;        // 0..8191
    t_[idx] = W[(size_t)(pr * 64 + (idx >> 7)) * 128 + (idx & 127)];
  }
  __syncthreads();
  const int l = t & 63, ot = t >> 6;
  const int kh = l >> 5, o = ot * 32 + (l & 31);
  u8 buf[32];
#pragma unroll
  for (int b = 0; b < 32; ++b)
    buf[b] = f2e4m3(64.f * t_[(kh * 32 + b) * 128 + o]);
  u8* d = wfr + (size_t)pr * 8192 + ot * 2048 + l * 32;
  *(uint4*)d = *(uint4*)buf;
  *(uint4*)(d + 16) = *(uint4*)(buf + 16);
}

// ---------- init: out = bias ----------
__global__ __launch_bounds__(256)
void init_out(const float* __restrict__ bias, float* __restrict__ out) {
  const int i4 = blockIdx.x * 256 + threadIdx.x;
  float4 b = ((const float4*)bias)[i4 & 31];
  ((float4*)out)[i4] = b;
}

// ---------- main: 1024 blocks(256thr) = 128 row-tiles(128r) x 8 center-eighths(512c) ----------
// Per block: 8 pairs. GEMM1 = 8 MX/chunk; GEMM2 = 4 MX/pair. Half the per-wave timeline of R19.
__global__ __launch_bounds__(256, 2)
void rbf_main(const u8* __restrict__ xfs, const u8* __restrict__ cfr,
              const u8* __restrict__ wfr, const float* __restrict__ csq_g,
              const float* __restrict__ xsq_g, float* __restrict__ out)
{
  __shared__ __align__(16) u8 cs[4][16384];   // center chunk 4-ring, 64 KB
  __shared__ __align__(16) float csq_l[512];
  __shared__ __align__(16) float xsq_l[128];

  const int tid = threadIdx.x;
  const int lane = tid & 63;
  const int wv = tid >> 6;                 // wave 0..3 -> rows wv*32..+32
  const int l31 = lane & 31;
  const int h = lane >> 5;
  const int bid = blockIdx.x;
  const int chq = bid & 7;                 // center eighth
  const size_t r0 = (size_t)(bid >> 3) * 128;

#define S_CS(cc) do { \
    const u8* sG_ = cfr + ((size_t)(chq * 16 + (cc)) << 14) + tid * 16; \
    u8* sL_ = &cs[(cc) & 3][0] + tid * 16; \
    GLOAD_LDS(sG_,         sL_); \
    GLOAD_LDS(sG_ + 4096,  sL_ + 4096); \
    GLOAD_LDS(sG_ + 8192,  sL_ + 8192); \
    GLOAD_LDS(sG_ + 12288, sL_ + 12288); \
  } while (0)

  // prologue staging: chunks 0,1 -> slots 0,1
  if (tid < 32)  GLOAD_LDS(xsq_g + r0 + tid * 4, xsq_l + tid * 4);
  if (tid < 128) GLOAD_LDS(csq_g + chq * 512 + tid * 4, csq_l + tid * 4);
  S_CS(0);
  S_CS(1);

  // x fragments: 8 x 32B (K=64 each)
  i32x8 xf8[8];
  {
    const u8* xb = xfs + ((size_t)((bid >> 3) * 4 + wv)) * 16384 + lane * 32;
#pragma unroll
    for (int P = 0; P < 8; ++P) {
      union { l64x2 q[2]; i32x8 v; } t;
      t.q[0] = *(const l64x2*)(xb + P * 2048);
      t.q[1] = *(const l64x2*)(xb + P * 2048 + 16);
      xf8[P] = t.v;
    }
  }

  asm volatile("s_waitcnt vmcnt(0)" ::: "memory");
  __builtin_amdgcn_s_barrier();
  __builtin_amdgcn_sched_barrier(0);

  const float xn = NB2 * xsq_l[wv * 32 + l31];

  const int swz = (lane >> 2) & 1;
  const int alo = lane * 32 + swz * 16;
  const int ahi = lane * 32 + (swz ^ 1) * 16;

  const f32x16 z16 = {0,0,0,0,0,0,0,0,0,0,0,0,0,0,0,0};
  f32x16 oa0 = z16, oa1 = z16, oa2 = z16, oa3 = z16;

// GEMM1 (swapped, MX) on chunk CC in ring slot SLOT, then exp+fp8-pack into O0..O3
#define G1EXP(CC, SLOT, O0, O1, O2, O3) do { \
    const u8* csb = &cs[SLOT][0]; \
    f32x16 s0 = z16, s1 = z16; \
    _Pragma("unroll") \
    for (int P = 0; P < 8; ++P) { \
      union { l64x2 q[2]; i32x8 v; } A; \
      A.q[0] = *(const l64x2*)(csb + P * 2048 + alo); \
      A.q[1] = *(const l64x2*)(csb + P * 2048 + ahi); \
      __builtin_amdgcn_s_setprio(1); \
      if (P & 1) s1 = MFS(A.v, xf8[P], s1); \
      else       s0 = MFS(A.v, xf8[P], s0); \
      __builtin_amdgcn_s_setprio(0); \
    } \
    f32x4 cq0 = *(const f32x4*)(csq_l + (CC) * 32 + 0  + 4 * h); \
    f32x4 cq1 = *(const f32x4*)(csq_l + (CC) * 32 + 8  + 4 * h); \
    f32x4 cq2 = *(const f32x4*)(csq_l + (CC) * 32 + 16 + 4 * h); \
    f32x4 cq3 = *(const f32x4*)(csq_l + (CC) * 32 + 24 + 4 * h); \
    float e[16]; \
    _Pragma("unroll") \
    for (int r = 0; r < 16; ++r) { \
      const float cq = (r < 4 ? cq0[r] : r < 8 ? cq1[r-4] : r < 12 ? cq2[r-8] : cq3[r-12]); \
      e[r] = __builtin_amdgcn_exp2f(fmaf(s0[r] + s1[r], P2C, fmaf(cq, NB2, xn))); \
    } \
    O0 = pk4(e[0],  e[1],  e[2],  e[3]); \
    O1 = pk4(e[4],  e[5],  e[6],  e[7]); \
    O2 = pk4(e[8],  e[9],  e[10], e[11]); \
    O3 = pk4(e[12], e[13], e[14], e[15]); \
  } while (0)

#pragma unroll 1
  for (int t = 0; t < 8; ++t) {
    // ---- W pair -> regs (coalesced, L2-hot; consumed ~4000cy later) ----
    const u8* wgb = wfr + ((size_t)(chq * 8 + t) << 13) + lane * 32;
    union { l64x2 q[2]; i32x8 v; } w0, w1, w2, w3;
    w0.q[0] = *(const l64x2*)(wgb);        w0.q[1] = *(const l64x2*)(wgb + 16);
    w1.q[0] = *(const l64x2*)(wgb + 2048); w1.q[1] = *(const l64x2*)(wgb + 2064);
    w2.q[0] = *(const l64x2*)(wgb + 4096); w2.q[1] = *(const l64x2*)(wgb + 4112);
    w3.q[0] = *(const l64x2*)(wgb + 6144); w3.q[1] = *(const l64x2*)(wgb + 6160);
    __builtin_amdgcn_sched_barrier(0);
    // ---- stage next pair into the free ring slots ----
    if (t < 7) { S_CS(2 * t + 2); S_CS(2 * t + 3); }
    __builtin_amdgcn_sched_barrier(0);

    unsigned D0, D1, D2, D3, E0, E1, E2, E3;
    G1EXP(2 * t,     (2 * t) & 3,     D0, D1, D2, D3);
    G1EXP(2 * t + 1, (2 * t + 1) & 3, E0, E1, E2, E3);

    // assemble pair A-operand: A[2i]=D_i, A[2i+1]=E_i after half-exchange
    pswap(D0, E0); pswap(D1, E1); pswap(D2, E2); pswap(D3, E3);
    union { unsigned u[8]; i32x8 v; } PA;
    PA.u[0] = D0; PA.u[1] = E0; PA.u[2] = D1; PA.u[3] = E1;
    PA.u[4] = D2; PA.u[5] = E2; PA.u[6] = D3; PA.u[7] = E3;

    // ---- GEMM2: 4 MX insts, K=64 (the pair), W scale 2^-6 ----
    __builtin_amdgcn_s_setprio(1);
    oa0 = MFS2(PA.v, w0.v, oa0);
    oa1 = MFS2(PA.v, w1.v, oa1);
    oa2 = MFS2(PA.v, w2.v, oa2);
    oa3 = MFS2(PA.v, w3.v, oa3);
    __builtin_amdgcn_s_setprio(0);

    // ring-slot reuse guard; staged DMAs are ~whole-iter old -> no stall
    asm volatile("s_waitcnt vmcnt(0)" ::: "memory");
    __builtin_amdgcn_s_barrier();
    __builtin_amdgcn_sched_barrier(0);
  }

  // epilogue: out += partial; D rows m=(r&3)+8*(r>>2)+4h, cols o=ot*32+l31
#pragma unroll
  for (int r = 0; r < 16; ++r) {
    const int m = wv * 32 + (r & 3) + 8 * (r >> 2) + 4 * h;
    float* op = &out[(r0 + m) * 128 + l31];
    atomicAdd(op,      oa0[r]);
    atomicAdd(op + 32, oa1[r]);
    atomicAdd(op + 64, oa2[r]);
    atomicAdd(op + 96, oa3[r]);
  }
#undef S_CS
#undef G1EXP
}

extern "C" void kernel_launch(void* const* d_in, const int* in_sizes, int n_in,
                              void* d_out, int out_size, void* d_ws, size_t ws_size,
                              hipStream_t stream) {
  (void)in_sizes; (void)n_in; (void)out_size; (void)ws_size;
  const float* x   = (const float*)d_in[0];
  const float* cen = (const float*)d_in[1];
  const float* W   = (const float*)d_in[2];
  const float* b   = (const float*)d_in[3];
  u8* xfs = (u8*)d_ws;                          // 8 MB (x K=64 frag-stream)
  u8* cfr = xfs + (size_t)16384 * 512;          // 2 MB (center K=64 frag-stream)
  u8* wfr = cfr + (size_t)4096 * 512;           // 512 KB (W fp8 x64 pair-stream)
  float* csq = (float*)(wfr + (size_t)64 * 8192);  // 16 KB
  float* xsq = csq + 4096;                      // 64 KB
  prep_x8<<<2048, 512, 0, stream>>>(x, xfs, xsq);
  prep_cen<<<1024, 256, 0, stream>>>(cen, cfr, csq);
  prep_w<<<64, 256, 0, stream>>>(W, wfr);
  init_out<<<2048, 256, 0, stream>>>(b, (float*)d_out);
  rbf_main<<<1024, 256, 0, stream>>>(xfs, cfr, wfr, csq, xsq, (float*)d_out);
}

// Round 21
// 87.890 us; speedup vs baseline: 1.3392x; 1.3392x over previous
//
#include <hip/hip_runtime.h>
#include <hip/hip_bf16.h>

typedef float f32x4 __attribute__((ext_vector_type(4)));
typedef float f32x16 __attribute__((ext_vector_type(16)));
typedef long l64x2 __attribute__((ext_vector_type(2)));
typedef int i32x8 __attribute__((ext_vector_type(8)));
typedef unsigned short u16;
typedef unsigned char u8;

#define NB2 (-0.35f * 1.44269504088896340736f)
#define P2C (0.70f * 1.44269504088896340736f)
// MX-scaled fp8 e4m3 (cbsz=0, blgp=0), scales 1.0
#define MFS(a,b,c) __builtin_amdgcn_mfma_scale_f32_32x32x64_f8f6f4( \
    a, b, c, 0, 0, 0, 0x7F7F7F7F, 0, 0x7F7F7F7F)
// GEMM2: A=P (scale 1.0), B=W stored x64 (scale 2^-6 = E8M0 121 = 0x79)
#define MFS2(a,b,c) __builtin_amdgcn_mfma_scale_f32_32x32x64_f8f6f4( \
    a, b, c, 0, 0, 0, 0x7F7F7F7F, 0, 0x79797979)

__device__ __forceinline__ void pswap(unsigned &a, unsigned &b) {
  asm volatile("v_permlane32_swap_b32 %0, %1" : "+v"(a), "+v"(b));
}

__device__ __forceinline__ u8 f2e4m3(float f) {
  unsigned int u = __float_as_uint(f);
  u8 s = (u8)((u >> 24) & 0x80u);
  float a = fabsf(f);
  if (a >= 448.f) return s | 0x7E;
  if (a < 0.015625f) return s | (u8)(int)rintf(a * 512.f);
  unsigned int m = u & 0x7fffffffu;
  unsigned int r = m + 0x7FFFFu + ((m >> 20) & 1u);
  return s | (u8)((((r >> 23) - 120u) << 3) | ((r >> 20) & 7u));
}

__device__ __forceinline__ unsigned int pk4(float a, float b, float c, float d) {
#if __has_builtin(__builtin_amdgcn_cvt_pk_fp8_f32)
  int v = __builtin_amdgcn_cvt_pk_fp8_f32(a, b, 0, false);
  v = __builtin_amdgcn_cvt_pk_fp8_f32(c, d, v, true);
  return (unsigned int)v;
#else
  return (unsigned int)f2e4m3(a) | ((unsigned int)f2e4m3(b) << 8)
       | ((unsigned int)f2e4m3(c) << 16) | ((unsigned int)f2e4m3(d) << 24);
#endif
}

#define GLOAD_LDS(g, l) __builtin_amdgcn_global_load_lds( \
    (const __attribute__((address_space(1))) unsigned int*)(g), \
    (__attribute__((address_space(3))) unsigned int*)(l), 16, 0, 0)

// ---------- prep: x -> fp8 K=64 frag-stream [tile32][P(8)][lane(64)][32B] + xsq ----------
__global__ __launch_bounds__(512)
void prep_x8(const float* __restrict__ src, u8* __restrict__ dst,
             float* __restrict__ sq) {
  const int row = blockIdx.x * 8 + (threadIdx.x >> 6);
  const int i6 = threadIdx.x & 63;
  const float4* p = (const float4*)(src + (size_t)row * 512) + i6 * 2;
  float4 a = p[0], b = p[1];
  float ss = a.x*a.x + a.y*a.y + a.z*a.z + a.w*a.w
           + b.x*b.x + b.y*b.y + b.z*b.z + b.w*b.w;
  uint2 o;
  o.x = pk4(a.x, a.y, a.z, a.w);
  o.y = pk4(b.x, b.y, b.z, b.w);
  const int P = i6 >> 3, rem = i6 & 7;
  const int kh = rem >> 2;
  const int l = (kh << 5) | (row & 31);
  *(uint2*)(dst + (size_t)(row >> 5) * 16384 + P * 2048 + l * 32 + (rem & 3) * 8) = o;
  ss += __shfl_xor(ss, 1);  ss += __shfl_xor(ss, 2);
  ss += __shfl_xor(ss, 4);  ss += __shfl_xor(ss, 8);
  ss += __shfl_xor(ss, 16); ss += __shfl_xor(ss, 32);
  if (i6 == 0) sq[row] = ss;
}

// ---------- prep: centers -> fp8 K=64 frag-stream with 16B-unit XOR swizzle + csq ----------
__global__ __launch_bounds__(256)
void prep_cen(const float* __restrict__ cen, u8* __restrict__ cfr,
              float* __restrict__ csq) {
  const int t = threadIdx.x;
  const int c = blockIdx.x * 4 + (t >> 6);
  const int i6 = t & 63;
  const float* p = cen + (size_t)c * 512 + i6 * 8;
  float4 a = *(const float4*)p, b = *(const float4*)(p + 4);
  float ss = a.x*a.x + a.y*a.y + a.z*a.z + a.w*a.w
           + b.x*b.x + b.y*b.y + b.z*b.z + b.w*b.w;
  uint2 o;
  o.x = pk4(a.x, a.y, a.z, a.w);
  o.y = pk4(b.x, b.y, b.z, b.w);
  const int P = i6 >> 3, rem = i6 & 7;
  const int kh = rem >> 2;
  const int lc = c & 31;
  const int l = (kh << 5) | lc;
  const int u = (rem >> 1) & 1;
  const int sub = rem & 1;
  const int us = u ^ ((lc >> 2) & 1);
  *(uint2*)(cfr + (size_t)(c >> 5) * 16384 + P * 2048 + l * 32 + us * 16 + sub * 8) = o;
  ss += __shfl_xor(ss, 1);  ss += __shfl_xor(ss, 2);
  ss += __shfl_xor(ss, 4);  ss += __shfl_xor(ss, 8);
  ss += __shfl_xor(ss, 16); ss += __shfl_xor(ss, 32);
  if (i6 == 0) csq[c] = ss;
}

// ---------- prep: W [4096][128] f32 -> fp8(x64) MX B-operand pair-stream ----------
// wfr[pair*8192 + ot*2048 + l*32 + b] = e4m3(64 * W[pair*64 + (l>>5)*32 + b][ot*32 + (l&31)])
__global__ __launch_bounds__(256)
void prep_w(const float* __restrict__ W, u8* __restrict__ wfr) {
  __shared__ float t_[64 * 128];   // 32 KB
  const int pr = blockIdx.x;       // pair 0..63
  const int t = threadIdx.x;
#pragma unroll
  for (int it = 0; it < 32; ++it) {
    int idx = it * 256 + t;        // 0..8191
    t_[idx] = W[(size_t)(pr * 64 + (idx >> 7)) * 128 + (idx & 127)];
  }
  __syncthreads();
  const int l = t & 63, ot = t >> 6;
  const int kh = l >> 5, o = ot * 32 + (l & 31);
  u8 buf[32];
#pragma unroll
  for (int b = 0; b < 32; ++b)
    buf[b] = f2e4m3(64.f * t_[(kh * 32 + b) * 128 + o]);
  u8* d = wfr + (size_t)pr * 8192 + ot * 2048 + l * 32;
  *(uint4*)d = *(uint4*)buf;
  *(uint4*)(d + 16) = *(uint4*)(buf + 16);
}

// ---------- init: out = bias ----------
__global__ __launch_bounds__(256)
void init_out(const float* __restrict__ bias, float* __restrict__ out) {
  const int i4 = blockIdx.x * 256 + threadIdx.x;
  float4 b = ((const float4*)bias)[i4 & 31];
  ((float4*)out)[i4] = b;
}

// ---------- main: 512 blocks(256thr) = 128 row-tiles(128r) x 4 quarters ----------
// Chunk-paired: GEMM1 = 8 MX/chunk; GEMM2 = 4 MX/pair (P in fp8, W fp8 x64 + HW scale 2^-6).
// cs 4-ring (pair dbuf); W via L2->regs; ONE barrier + stale vmcnt(0) per pair.
__global__ __launch_bounds__(256, 2)
void rbf_main(const u8* __restrict__ xfs, const u8* __restrict__ cfr,
              const u8* __restrict__ wfr, const float* __restrict__ csq_g,
              const float* __restrict__ xsq_g, float* __restrict__ out)
{
  __shared__ __align__(16) u8 cs[4][16384];   // center chunk 4-ring, 64 KB
  __shared__ __align__(16) float csq_l[1024];
  __shared__ __align__(16) float xsq_l[128];

  const int tid = threadIdx.x;
  const int lane = tid & 63;
  const int wv = tid >> 6;                 // wave 0..3 -> rows wv*32..+32
  const int l31 = lane & 31;
  const int h = lane >> 5;
  const int bid = blockIdx.x;
  const int chq = bid & 3;
  const size_t r0 = (size_t)(bid >> 2) * 128;

#define S_CS(cc) do { \
    const u8* sG_ = cfr + ((size_t)(chq * 32 + (cc)) << 14) + tid * 16; \
    u8* sL_ = &cs[(cc) & 3][0] + tid * 16; \
    GLOAD_LDS(sG_,         sL_); \
    GLOAD_LDS(sG_ + 4096,  sL_ + 4096); \
    GLOAD_LDS(sG_ + 8192,  sL_ + 8192); \
    GLOAD_LDS(sG_ + 12288, sL_ + 12288); \
  } while (0)

  // prologue staging: chunks 0,1 -> slots 0,1
  if (tid < 32) GLOAD_LDS(xsq_g + r0 + tid * 4, xsq_l + tid * 4);
  GLOAD_LDS(csq_g + chq * 1024 + tid * 4, csq_l + tid * 4);
  S_CS(0);
  S_CS(1);

  // x fragments: 8 x 32B (K=64 each)
  i32x8 xf8[8];
  {
    const u8* xb = xfs + ((size_t)((bid >> 2) * 4 + wv)) * 16384 + lane * 32;
#pragma unroll
    for (int P = 0; P < 8; ++P) {
      union { l64x2 q[2]; i32x8 v; } t;
      t.q[0] = *(const l64x2*)(xb + P * 2048);
      t.q[1] = *(const l64x2*)(xb + P * 2048 + 16);
      xf8[P] = t.v;
    }
  }

  asm volatile("s_waitcnt vmcnt(0)" ::: "memory");
  __builtin_amdgcn_s_barrier();
  __builtin_amdgcn_sched_barrier(0);

  const float xn = NB2 * xsq_l[wv * 32 + l31];

  const int swz = (lane >> 2) & 1;
  const int alo = lane * 32 + swz * 16;
  const int ahi = lane * 32 + (swz ^ 1) * 16;

  const f32x16 z16 = {0,0,0,0,0,0,0,0,0,0,0,0,0,0,0,0};
  f32x16 oa0 = z16, oa1 = z16, oa2 = z16, oa3 = z16;

// GEMM1 (swapped, MX) on chunk CC in ring slot SLOT, then exp+fp8-pack into O0..O3
#define G1EXP(CC, SLOT, O0, O1, O2, O3) do { \
    const u8* csb = &cs[SLOT][0]; \
    f32x16 s0 = z16, s1 = z16; \
    _Pragma("unroll") \
    for (int P = 0; P < 8; ++P) { \
      union { l64x2 q[2]; i32x8 v; } A; \
      A.q[0] = *(const l64x2*)(csb + P * 2048 + alo); \
      A.q[1] = *(const l64x2*)(csb + P * 2048 + ahi); \
      __builtin_amdgcn_s_setprio(1); \
      if (P & 1) s1 = MFS(A.v, xf8[P], s1); \
      else       s0 = MFS(A.v, xf8[P], s0); \
      __builtin_amdgcn_s_setprio(0); \
    } \
    f32x4 cq0 = *(const f32x4*)(csq_l + (CC) * 32 + 0  + 4 * h); \
    f32x4 cq1 = *(const f32x4*)(csq_l + (CC) * 32 + 8  + 4 * h); \
    f32x4 cq2 = *(const f32x4*)(csq_l + (CC) * 32 + 16 + 4 * h); \
    f32x4 cq3 = *(const f32x4*)(csq_l + (CC) * 32 + 24 + 4 * h); \
    float e[16]; \
    _Pragma("unroll") \
    for (int r = 0; r < 16; ++r) { \
      const float cq = (r < 4 ? cq0[r] : r < 8 ? cq1[r-4] : r < 12 ? cq2[r-8] : cq3[r-12]); \
      e[r] = __builtin_amdgcn_exp2f(fmaf(s0[r] + s1[r], P2C, fmaf(cq, NB2, xn))); \
    } \
    O0 = pk4(e[0],  e[1],  e[2],  e[3]); \
    O1 = pk4(e[4],  e[5],  e[6],  e[7]); \
    O2 = pk4(e[8],  e[9],  e[10], e[11]); \
    O3 = pk4(e[12], e[13], e[14], e[15]); \
  } while (0)

#pragma unroll 1
  for (int t = 0; t < 16; ++t) {
    // ---- W pair t -> regs (coalesced, L2-hot; consumed ~4000cy later) ----
    const u8* wgb = wfr + ((size_t)(chq * 16 + t) << 13) + lane * 32;
    union { l64x2 q[2]; i32x8 v; } w0, w1, w2, w3;
    w0.q[0] = *(const l64x2*)(wgb);        w0.q[1] = *(const l64x2*)(wgb + 16);
    w1.q[0] = *(const l64x2*)(wgb + 2048); w1.q[1] = *(const l64x2*)(wgb + 2064);
    w2.q[0] = *(const l64x2*)(wgb + 4096); w2.q[1] = *(const l64x2*)(wgb + 4112);
    w3.q[0] = *(const l64x2*)(wgb + 6144); w3.q[1] = *(const l64x2*)(wgb + 6160);
    __builtin_amdgcn_sched_barrier(0);
    // ---- stage next pair into the free ring slots ----
    if (t < 15) { S_CS(2 * t + 2); S_CS(2 * t + 3); }
    __builtin_amdgcn_sched_barrier(0);

    unsigned D0, D1, D2, D3, E0, E1, E2, E3;
    G1EXP(2 * t,     (2 * t) & 3,     D0, D1, D2, D3);
    G1EXP(2 * t + 1, (2 * t + 1) & 3, E0, E1, E2, E3);

    // assemble pair A-operand: A[2i]=D_i, A[2i+1]=E_i after half-exchange
    pswap(D0, E0); pswap(D1, E1); pswap(D2, E2); pswap(D3, E3);
    union { unsigned u[8]; i32x8 v; } PA;
    PA.u[0] = D0; PA.u[1] = E0; PA.u[2] = D1; PA.u[3] = E1;
    PA.u[4] = D2; PA.u[5] = E2; PA.u[6] = D3; PA.u[7] = E3;

    // ---- GEMM2: 4 MX insts, K=64 (the pair), W scale 2^-6 ----
    __builtin_amdgcn_s_setprio(1);
    oa0 = MFS2(PA.v, w0.v, oa0);
    oa1 = MFS2(PA.v, w1.v, oa1);
    oa2 = MFS2(PA.v, w2.v, oa2);
    oa3 = MFS2(PA.v, w3.v, oa3);
    __builtin_amdgcn_s_setprio(0);

    // ring-slot reuse guard; staged DMAs are ~whole-iter old -> no stall
    asm volatile("s_waitcnt vmcnt(0)" ::: "memory");
    __builtin_amdgcn_s_barrier();
    __builtin_amdgcn_sched_barrier(0);
  }

  // epilogue: out += partial; D rows m=(r&3)+8*(r>>2)+4h, cols o=ot*32+l31
#pragma unroll
  for (int r = 0; r < 16; ++r) {
    const int m = wv * 32 + (r & 3) + 8 * (r >> 2) + 4 * h;
    float* op = &out[(r0 + m) * 128 + l31];
    atomicAdd(op,      oa0[r]);
    atomicAdd(op + 32, oa1[r]);
    atomicAdd(op + 64, oa2[r]);
    atomicAdd(op + 96, oa3[r]);
  }
#undef S_CS
#undef G1EXP
}

extern "C" void kernel_launch(void* const* d_in, const int* in_sizes, int n_in,
                              void* d_out, int out_size, void* d_ws, size_t ws_size,
                              hipStream_t stream) {
  (void)in_sizes; (void)n_in; (void)out_size; (void)ws_size;
  const float* x   = (const float*)d_in[0];
  const float* cen = (const float*)d_in[1];
  const float* W   = (const float*)d_in[2];
  const float* b   = (const float*)d_in[3];
  u8* xfs = (u8*)d_ws;                          // 8 MB (x K=64 frag-stream)
  u8* cfr = xfs + (size_t)16384 * 512;          // 2 MB (center K=64 frag-stream)
  u8* wfr = cfr + (size_t)4096 * 512;           // 512 KB (W fp8 x64 pair-stream)
  float* csq = (float*)(wfr + (size_t)64 * 8192);  // 16 KB
  float* xsq = csq + 4096;                      // 64 KB
  prep_x8<<<2048, 512, 0, stream>>>(x, xfs, xsq);
  prep_cen<<<1024, 256, 0, stream>>>(cen, cfr, csq);
  prep_w<<<64, 256, 0, stream>>>(W, wfr);
  init_out<<<2048, 256, 0, stream>>>(b, (float*)d_out);
  rbf_main<<<512, 256, 0, stream>>>(xfs, cfr, wfr, csq, xsq, (float*)d_out);
}